// Round 17
// baseline (776.540 us; speedup 1.0000x reference)
//
#include <hip/hip_runtime.h>
#include <hip/hip_bf16.h>

typedef __hip_bfloat16 bf16;

#define PLW 320  // max uk-phase width

// ---------------- constant tables ----------------
// Y layout uses permuted path order [0,1,3,2,4,5,6,7,8,9,10] so the 5
// fully load-balanced (un=4) w-con phases are contiguous in Y.
__constant__ int d_ybnd[12] = {0,64,96,288,304,400,496,544,864,1024,1104,1184}; // slot bounds
__constant__ int d_yperm[11]= {0,1,3,2,4,5,6,7,8,9,10};                         // slot -> path
__constant__ int d_pl1[11]  = {0,1,2,0,1,1,2,0,1,2,2};
__constant__ int d_pl2[11]  = {0,1,2,1,0,2,1,2,1,0,2};
__constant__ int d_plo[11]  = {0,0,0,1,1,1,1,2,2,2,2};
__constant__ int d_cgoffE[12]= {0,1,10,35,44,53,98,143,168,213,238,363};
__constant__ int d_woff[11] = {0,4096,6144,7168,9216,10240,11264,11776,12800,13312,13568};
__constant__ int d_dims[3]  = {1,3,5};
__constant__ int d_muls[3]  = {64,32,16};
__constant__ int d_segb[3]  = {0,64,160};
__constant__ int d_shb[3]   = {0,1,4};
__constant__ int d_phb5[6]  = {0,64,288,544,864,1184};  // 5 phase bases (path-aligned in permuted Y)
__constant__ int d_obeg5[5] = {0,0,0,160,160};          // per-phase agg output range
__constant__ int d_oend5[5] = {64,160,160,240,240};

// ---------------- dtype flag + input conversion ----------------
__global__ void k_flag(const unsigned int* w, int* flag){
  if (threadIdx.x==0 && blockIdx.x==0) *flag = (w[0] == 0x3F800000u) ? 0 : 1;
}

struct CvtTab { const void* src[15]; int off[15]; int cnt[15]; int total; };

__global__ void __launch_bounds__(256) k_convert(CvtTab tab, const int* __restrict__ flag,
                                                 float* __restrict__ wf){
  int f = *flag;
  int idx = blockIdx.x*256 + threadIdx.x;
  if (idx >= tab.total) return;
  int a = idx, s = 0;
  while (a >= tab.cnt[s]){ a -= tab.cnt[s]; s++; }
  float v;
  if (f) v = __bfloat162float(((const bf16*)tab.src[s])[a]);
  else   v = ((const float*)tab.src[s])[a];
  wf[tab.off[s] + a] = v;
}

// wm3/bm3 -> bf16 directly from raw inputs (bf16 input: pure copy; f32: convert)
__global__ void __launch_bounds__(256) k_wcvt2(const void* __restrict__ wm3raw,
                  const void* __restrict__ bm3raw, const int* __restrict__ flag,
                  ushort* __restrict__ dst){
  int i = blockIdx.x*256 + threadIdx.x;
  if (i >= 5349888) return;
  int f = *flag;
  if (i < 5308416){
    if (f) dst[i] = ((const ushort*)wm3raw)[i];
    else   dst[i] = (ushort)(__hip_bfloat16_raw(__float2bfloat16(((const float*)wm3raw)[i])).x);
  } else {
    int a = i - 5308416;
    if (f) dst[i] = ((const ushort*)bm3raw)[a];
    else   dst[i] = (ushort)(__hip_bfloat16_raw(__float2bfloat16(((const float*)bm3raw)[a])).x);
  }
}

// ---------------- CG tensors (parallel: 1 thread per entry, same f64 math) ----------------
__device__ double dfact_d(int n){ double r=1.0; while(n>1){ r*=n; n-=2; } return r; }
__device__ double mavg_d(int a,int b,int c){
  if ((a&1)||(b&1)||(c&1)) return 0.0;
  return dfact_d(a-1)*dfact_d(b-1)*dfact_d(c-1)/dfact_d(a+b+c+1);
}

__global__ void __launch_bounds__(384) k_cg(float* cg){
  __shared__ double Gs[363];
  __shared__ double scl[11];
  int t = threadIdx.x;
  const double s3 = sqrt(3.0), s5 = sqrt(5.0), s15 = sqrt(15.0);
  int cnt[3][5]; double cf[3][5][2]; int ex[3][5][2][3];
  for (int l=0;l<3;l++) for (int m=0;m<5;m++){
    cnt[l][m]=0;
    for (int q=0;q<2;q++){ cf[l][m][q]=0.0; for(int a=0;a<3;a++) ex[l][m][q][a]=0; }
  }
  cnt[0][0]=1; cf[0][0][0]=1.0;
  cnt[1][0]=1; cf[1][0][0]=s3; ex[1][0][0][0]=1;
  cnt[1][1]=1; cf[1][1][0]=s3; ex[1][1][0][1]=1;
  cnt[1][2]=1; cf[1][2][0]=s3; ex[1][2][0][2]=1;
  cnt[2][0]=1; cf[2][0][0]=s15; ex[2][0][0][0]=1; ex[2][0][0][1]=1;
  cnt[2][1]=1; cf[2][1][0]=s15; ex[2][1][0][1]=1; ex[2][1][0][2]=1;
  cnt[2][2]=2; cf[2][2][0]=1.5*s5; ex[2][2][0][2]=2; cf[2][2][1]=-0.5*s5;
  cnt[2][3]=1; cf[2][3][0]=s15; ex[2][3][0][0]=1; ex[2][3][0][2]=1;
  cnt[2][4]=2; cf[2][4][0]=0.5*s15; ex[2][4][0][0]=2; cf[2][4][1]=-0.5*s15; ex[2][4][1][1]=2;
  if (t < 363){
    int p=0; while (t >= d_cgoffE[p+1]) p++;
    int l1=d_pl1[p], l2=d_pl2[p], l3=d_plo[p];
    int n2=2*l2+1, n3=2*l3+1;
    int loc = t - d_cgoffE[p];
    int k = loc % n3; int ij = loc / n3; int j = ij % n2; int i = ij / n2;
    double s=0.0;
    for (int t1=0;t1<cnt[l1][i];t1++)
      for (int t2=0;t2<cnt[l2][j];t2++)
        for (int t3=0;t3<cnt[l3][k];t3++){
          int a=ex[l1][i][t1][0]+ex[l2][j][t2][0]+ex[l3][k][t3][0];
          int b=ex[l1][i][t1][1]+ex[l2][j][t2][1]+ex[l3][k][t3][1];
          int c=ex[l1][i][t1][2]+ex[l2][j][t2][2]+ex[l3][k][t3][2];
          s += cf[l1][i][t1]*cf[l2][j][t2]*cf[l3][k][t3]*mavg_d(a,b,c);
        }
    Gs[t] = s;
  }
  __syncthreads();
  if (t < 11){
    double ssq=0.0;
    for (int q=d_cgoffE[t]; q<d_cgoffE[t+1]; q++) ssq += Gs[q]*Gs[q];
    scl[t] = sqrt((double)(2*d_plo[t]+1)/ssq);
  }
  __syncthreads();
  if (t < 363){
    int p=0; while (t >= d_cgoffE[p+1]) p++;
    cg[t] = (float)(Gs[t]*scl[p]);
  }
}

// ---------------- edge geometry ----------------
__global__ void __launch_bounds__(256) k0a(const float* __restrict__ posf, float* __restrict__ ef,
                   float* __restrict__ erbf, float* __restrict__ esh){
  int e = blockIdx.x*256 + threadIdx.x;
  if (e >= 6400) return;
  int b = e/1600; int r1 = e - b*1600; int i = r1/40; int j = r1 - i*40;
  float dx = posf[(b*40+j)*3+0] - posf[(b*40+i)*3+0];
  float dy = posf[(b*40+j)*3+1] - posf[(b*40+i)*3+1];
  float dz = posf[(b*40+j)*3+2] - posf[(b*40+i)*3+2];
  float sq = dx*dx+dy*dy+dz*dz;
  float em = (sq <= 36.f && sq > 1e-16f) ? 1.f : 0.f;
  ef[e] = em;
  float elen = (sq > 1e-12f) ? sqrtf(sq) : 0.f;
  float inv = 1.f/fmaxf(elen, 1e-8f);
  float x = dx*inv, y = dy*inv, z = dz*inv;
  float rc = fminf(elen, 6.f);
  #pragma unroll
  for (int k=0;k<16;k++){ float d = rc - 0.4f*(float)k; erbf[e*16+k] = expf(-6.25f*d*d); }
  const float S3=1.7320508075688772f, S5=2.23606797749979f, S15=3.872983346207417f;
  float* sh = esh + e*9;
  sh[0]=1.f; sh[1]=S3*x; sh[2]=S3*y; sh[3]=S3*z;
  sh[4]=S15*x*y; sh[5]=S15*y*z; sh[6]=0.5f*S5*(3.f*z*z-1.f); sh[7]=S15*x*z; sh[8]=0.5f*S15*(x*x-y*y);
}

// ---------------- node init + neighbor edge-list (deterministic ballot order, padded to even) ----------------
__global__ void __launch_bounds__(64) k0b(const int* __restrict__ z, const float* __restrict__ posf,
                  const float* __restrict__ zembf, const float* __restrict__ w_inf,
                  const float* __restrict__ ef,
                  float* __restrict__ x, float* __restrict__ deg,
                  int* __restrict__ nlist, int* __restrict__ ndeg2,
                  float* __restrict__ h2){
  int n = blockIdx.x; int lane = threadIdx.x;
  int b = n/40; int i = n - b*40;
  __shared__ float sc[81];
  float dx = posf[n*3+0]-posf[b*120+0];
  float dy = posf[n*3+1]-posf[b*120+1];
  float dz = posf[n*3+2]-posf[b*120+2];
  float sq = dx*dx+dy*dy+dz*dz;
  float r = (sq>1e-12f)? sqrtf(sq) : 0.f;
  sc[lane] = zembf[z[n]*64+lane];
  if (lane == 0) sc[64] = (i==0)?1.f:0.f;
  if (lane < 16){ float d = fminf(r,6.f)-0.4f*(float)lane; sc[65+lane] = expf(-6.25f*d*d); }
  // edge from src=lane to dst=i: e = b*1600 + lane*40 + i
  bool live = (lane < 40) && (ef[b*1600 + lane*40 + i] > 0.f);
  unsigned long long m = __ballot(live);
  if (live){
    int pos = __popcll(m & ((1ull<<lane)-1ull));
    nlist[n*64 + pos] = b*1600 + lane*40 + i;
  }
  if (lane == 0){
    int dg = __popcll(m);
    int dgp = (dg+1) & ~1;                 // pad to even with dummy edge 6400
    if (dg & 1) nlist[n*64 + dg] = 6400;
    ndeg2[n] = dgp;
    deg[n] = fmaxf((float)dg, 1.f);
  }
  if (n == 0){                             // zero dummy h2 row once per launch
    for (int c = lane; c < 129; c += 64) h2[6400*129 + c] = 0.f;
  }
  __syncthreads();
  float a = 0.f;
  for (int s=0;s<81;s++) a += sc[s]*w_inf[s*64+lane];
  x[n*240+lane] = a/9.f;
  for (int c = 64+lane; c < 240; c += 64) x[n*240+c] = 0.f;
}

// ---------------- fused edge MLP + Y (1 edge/block; also zeroes agg) ----------------
__global__ void __launch_bounds__(128) k12(const float* __restrict__ erbf, const float* __restrict__ wm1,
                   const float* __restrict__ bm1, const float* __restrict__ wm2,
                   const float* __restrict__ bm2, const float* __restrict__ ef,
                   const float* __restrict__ x, const float* __restrict__ esh,
                   const float* __restrict__ cg,
                   float* __restrict__ h2, float* __restrict__ Y, float* __restrict__ agg){
  int e = blockIdx.x;
  int t = threadIdx.x;
  if (e < 160){                            // zero agg for this layer (before any early exit)
    agg[e*240 + t] = 0.f;
    if (t < 112) agg[e*240 + 128 + t] = 0.f;
  }
  if (ef[e] == 0.f) return;                // uniform branch: whole block exits
  __shared__ float h1L[128];
  __shared__ float xL[240];
  __shared__ float cgL[363];
  // ---- edge MLP ----
  float a = bm1[t];
  #pragma unroll
  for (int k=0;k<16;k++) a += erbf[e*16+k]*wm1[k*128+t];
  h1L[t] = a/(1.f+expf(-a));
  int src = e/40;
  for (int c = t; c < 240; c += 128) xL[c] = x[src*240+c];
  for (int c = t; c < 363; c += 128) cgL[c] = cg[c];
  __syncthreads();
  float a2 = bm2[t];
  #pragma unroll 8
  for (int k=0;k<128;k++) a2 += h1L[k]*wm2[k*128+t];
  float s = a2/(1.f+expf(-a2));
  h2[e*129+t] = s;
  if (t==0) h2[e*129+128] = 1.f;
  // ---- Y (permuted layout) ----
  float sh[9];
  #pragma unroll
  for (int q=0;q<9;q++) sh[q] = esh[e*9+q];
  int s2 = 0;
  for (int uk = t; uk < 1184; uk += 128){
    while (uk >= d_ybnd[s2+1]) s2++;
    int p = d_yperm[s2];
    int l1 = d_pl1[p], l2 = d_pl2[p], lo = d_plo[p];
    int dim1 = d_dims[l1], dim2 = d_dims[l2], dimo = d_dims[lo];
    int loc = uk - d_ybnd[s2];
    int u = loc/dimo; int k = loc - u*dimo;
    const float* C = cgL + d_cgoffE[p];
    int xb = d_segb[l1] + u*dim1;
    int shb = d_shb[l2];
    float acc = 0.f;
    for (int i2=0;i2<dim1;i2++){
      float Dik = 0.f;
      for (int j2=0;j2<dim2;j2++) Dik += sh[shb+j2]*C[(i2*dim2+j2)*dimo + k];
      acc += xL[xb+i2]*Dik;
    }
    Y[(size_t)e*1184+uk] = acc;
  }
}

// ---------------- w-contraction: bf16 via uint2, 4 w per thread, un=4, h x2 unroll ----------------
template<int DD>
__device__ __forceinline__ void wcon(const ushort* __restrict__ wm3t, const ushort* __restrict__ bm3t,
    int h0, bool bias, const float* PLb, int wc, int Wp, int u0, int un,
    float* aggL, int outb){
  float acc[4*DD];
  #pragma unroll
  for (int q=0;q<4*DD;q++) acc[q]=0.f;
  for (int h=0; h<16; h+=2){
    const ushort* wrow0 = wm3t + (size_t)(h0+h)*13824 + wc;
    const ushort* wrow1 = wrow0 + 13824;
    const float* pr0 = PLb + h*PLW;
    const float* pr1 = pr0 + PLW;
    #pragma unroll 4
    for (int u=u0; u<u0+un; u++){
      uint2 wv0 = *(const uint2*)(wrow0 + u*Wp);
      uint2 wv1 = *(const uint2*)(wrow1 + u*Wp);
      const float* pp0 = pr0 + u*DD;
      const float* pp1 = pr1 + u*DD;
      #pragma unroll
      for (int k=0;k<DD;k++){
        float pv0 = pp0[k], pv1 = pp1[k];
        acc[0*DD+k] += __uint_as_float(wv0.x << 16)*pv0 + __uint_as_float(wv1.x << 16)*pv1;
        acc[1*DD+k] += __uint_as_float(wv0.x & 0xFFFF0000u)*pv0 + __uint_as_float(wv1.x & 0xFFFF0000u)*pv1;
        acc[2*DD+k] += __uint_as_float(wv0.y << 16)*pv0 + __uint_as_float(wv1.y << 16)*pv1;
        acc[3*DD+k] += __uint_as_float(wv0.y & 0xFFFF0000u)*pv0 + __uint_as_float(wv1.y & 0xFFFF0000u)*pv1;
      }
    }
  }
  if (bias){
    const ushort* wrow = bm3t + wc;
    const float* pr = PLb + 16*PLW;
    #pragma unroll 4
    for (int u=u0; u<u0+un; u++){
      uint2 wv = *(const uint2*)(wrow + u*Wp);
      const float* pp = pr + u*DD;
      #pragma unroll
      for (int k=0;k<DD;k++){
        float pv = pp[k];
        acc[0*DD+k] += __uint_as_float(wv.x << 16)*pv;
        acc[1*DD+k] += __uint_as_float(wv.x & 0xFFFF0000u)*pv;
        acc[2*DD+k] += __uint_as_float(wv.y << 16)*pv;
        acc[3*DD+k] += __uint_as_float(wv.y & 0xFFFF0000u)*pv;
      }
    }
  }
  #pragma unroll
  for (int j=0;j<4;j++)
    #pragma unroll
    for (int k=0;k<DD;k++)
      atomicAdd(&aggL[outb + j*DD + k], acc[j*DD+k]);
}

// ---------------- fused TP: P-build (edge-list, x2 unroll = round-15) + w-contraction ----------------
// grid (160, 8, 5): x = node n (fastest), y = h-chunk hc of 16 [+bias row hc==7], z = phase.
__global__ void __launch_bounds__(256) k34(const float* __restrict__ h2,
        const float* __restrict__ Y, const ushort* __restrict__ wm3t,
        const ushort* __restrict__ bm3t, const int* __restrict__ nlist,
        const int* __restrict__ ndeg2, float* __restrict__ agg){
  __shared__ float PL[17*PLW];
  __shared__ float aggL[240];
  int n = blockIdx.x, hc = blockIdx.y, ph = blockIdx.z;
  int t = threadIdx.x;
  int h0 = hc*16;
  bool bias = (hc==7);
  const int* nl = nlist + n*64;
  int dg2 = ndeg2[n];
  for (int q=t; q<240; q+=256) aggL[q]=0.f;

  int base = d_phb5[ph], width = d_phb5[ph+1] - base;
  // ---- P-build: PL[h, c] = sum_q h2[e_q, h0+h] * Y[e_q, base+c], 2 edges in flight ----
  for (int cc = t; cc < width; cc += 256){
    float pacc[17];
    #pragma unroll
    for (int h=0;h<17;h++) pacc[h]=0.f;
    for (int q=0; q<dg2; q+=2){
      int e0 = nl[q], e1 = nl[q+1];                       // wave-uniform s_loads
      float yv0 = Y[(size_t)e0*1184 + base + cc];
      float yv1 = Y[(size_t)e1*1184 + base + cc];
      const float* hh0 = h2 + e0*129 + h0;
      const float* hh1 = h2 + e1*129 + h0;
      #pragma unroll
      for (int h=0;h<17;h++) pacc[h] += yv0*hh0[h] + yv1*hh1[h];
    }
    #pragma unroll
    for (int h=0;h<17;h++) PL[h*PLW+cc] = pacc[h];
  }
  __syncthreads();
  // ---- w-contraction: every thread un=4 (64-load chain, 8 in flight via h x2) ----
  if (ph==0){        // {p0}
    { int w4=t&15; int uc=t>>4;          wcon<1>(wm3t,bm3t,h0,bias, PL+0,   d_woff[0]+w4*4, 64, uc*4, 4, aggL, 0+w4*4); }
  } else if (ph==1){ // {p1 yloc 0, p3 yloc 32}
    if      (t<128){ int w4=t&15; int uc=t>>4;            wcon<1>(wm3t,bm3t,h0,bias, PL+0,  d_woff[1]+w4*4, 64, uc*4, 4, aggL, 0+w4*4); }
    else           { int tt=t-128; int w4=tt&7; int uc=tt>>3; wcon<3>(wm3t,bm3t,h0,bias, PL+32, d_woff[3]+w4*4, 32, uc*4, 4, aggL, 64+w4*12); }
  } else if (ph==2){ // {p2 yloc 0, p4 yloc 16, p5 yloc 112, p6 yloc 208}
    if      (t<64) { int w4=t&15; int uc=t>>4;            wcon<1>(wm3t,bm3t,h0,bias, PL+0,   d_woff[2]+w4*4, 64, uc*4, 4, aggL, 0+w4*4); }
    else if (t<128){ int tt=t-64;  int w4=tt&7; int uc=tt>>3; wcon<3>(wm3t,bm3t,h0,bias, PL+16,  d_woff[4]+w4*4, 32, uc*4, 4, aggL, 64+w4*12); }
    else if (t<192){ int tt=t-128; int w4=tt&7; int uc=tt>>3; wcon<3>(wm3t,bm3t,h0,bias, PL+112, d_woff[5]+w4*4, 32, uc*4, 4, aggL, 64+w4*12); }
    else if (t<224){ int tt=t-192; int w4=tt&7; int uc=tt>>3; wcon<3>(wm3t,bm3t,h0,bias, PL+208, d_woff[6]+w4*4, 32, uc*4, 4, aggL, 64+w4*12); }
  } else if (ph==3){ // {p7}
    if (t<64)      { int w4=t&3; int uc=t>>2;             wcon<5>(wm3t,bm3t,h0,bias, PL+0,   d_woff[7]+w4*4, 16, uc*4, 4, aggL, 160+w4*20); }
  } else {           // {p8 yloc 0, p9 yloc 160, p10 yloc 240}
    if      (t<32) { int w4=t&3; int uc=t>>2;             wcon<5>(wm3t,bm3t,h0,bias, PL+0,   d_woff[8]+w4*4, 16, uc*4, 4, aggL, 160+w4*20); }
    else if (t<48) { int tt=t-32; int w4=tt&3; int uc=tt>>2; wcon<5>(wm3t,bm3t,h0,bias, PL+160, d_woff[9]+w4*4, 16, uc*4, 4, aggL, 160+w4*20); }
    else if (t<64) { int tt=t-48; int w4=tt&3; int uc=tt>>2; wcon<5>(wm3t,bm3t,h0,bias, PL+240, d_woff[10]+w4*4,16, uc*4, 4, aggL, 160+w4*20); }
  }
  __syncthreads();
  int beg = d_obeg5[ph], end = d_oend5[ph];
  for (int q = beg + t; q < end; q += 256) atomicAdd(&agg[n*240 + q], aggL[q]);
}

// ---------------- node update: x += irlin(x,ws) + irlin(agg_scaled,wo) ----------------
__global__ void __launch_bounds__(256) k5_update(const float* __restrict__ x, const float* __restrict__ agg,
    const float* __restrict__ deg,
    const float* __restrict__ ws0,const float* __restrict__ ws1,const float* __restrict__ ws2,
    const float* __restrict__ wo0,const float* __restrict__ wo1,const float* __restrict__ wo2,
    float* __restrict__ xn){
  int n = blockIdx.x; int t = threadIdx.x;
  __shared__ float xr[240], ar[240];
  float dg = deg[n];
  if (t < 240){
    float fan = (t<64)?112.f:((t<160)?144.f:128.f);
    xr[t] = x[n*240+t];
    ar[t] = agg[n*240+t]/(sqrtf(fan)*dg);
  }
  __syncthreads();
  if (t < 240){
    int lo  = (t<64)?0:((t<160)?1:2);
    int base= (lo==0)?0:((lo==1)?64:160);
    int mul = (lo==0)?64:((lo==1)?32:16);
    int d   = (lo==0)?1:((lo==1)?3:5);
    int loc = t - base; int wi = loc/d; int dd = loc - wi*d;
    const float* Ws = (lo==0)?ws0:((lo==1)?ws1:ws2);
    const float* Wo = (lo==0)?wo0:((lo==1)?wo1:wo2);
    float s1=0.f, s2=0.f;
    for (int u=0; u<mul; u++){
      s1 += xr[base+u*d+dd]*Ws[u*mul+wi];
      s2 += ar[base+u*d+dd]*Wo[u*mul+wi];
    }
    xn[n*240+t] = xr[t] + (s1+s2)*rsqrtf((float)mul);
  }
}

// ---------------- last-layer node update + fused LayerNorm -> d_out ----------------
__global__ void __launch_bounds__(256) k5_ln(const float* __restrict__ x, const float* __restrict__ agg,
    const float* __restrict__ deg,
    const float* __restrict__ ws0,const float* __restrict__ ws1,const float* __restrict__ ws2,
    const float* __restrict__ wo0,const float* __restrict__ wo1,const float* __restrict__ wo2,
    const float* __restrict__ g, const float* __restrict__ b2,
    const int* __restrict__ flag, void* outv){
  int n = blockIdx.x; int t = threadIdx.x;
  __shared__ float xr[240], ar[240];
  __shared__ float red[256];
  float dg = deg[n];
  if (t < 240){
    float fan = (t<64)?112.f:((t<160)?144.f:128.f);
    xr[t] = x[n*240+t];
    ar[t] = agg[n*240+t]/(sqrtf(fan)*dg);
  }
  __syncthreads();
  float val = 0.f;
  if (t < 240){
    int lo  = (t<64)?0:((t<160)?1:2);
    int base= (lo==0)?0:((lo==1)?64:160);
    int mul = (lo==0)?64:((lo==1)?32:16);
    int d   = (lo==0)?1:((lo==1)?3:5);
    int loc = t - base; int wi = loc/d; int dd = loc - wi*d;
    const float* Ws = (lo==0)?ws0:((lo==1)?ws1:ws2);
    const float* Wo = (lo==0)?wo0:((lo==1)?wo1:wo2);
    float s1=0.f, s2=0.f;
    for (int u=0; u<mul; u++){
      s1 += xr[base+u*d+dd]*Ws[u*mul+wi];
      s2 += ar[base+u*d+dd]*Wo[u*mul+wi];
    }
    val = xr[t] + (s1+s2)*rsqrtf((float)mul);
  }
  red[t] = (t<240) ? val : 0.f;
  __syncthreads();
  #pragma unroll
  for (int s=128; s>=1; s>>=1){
    if (t < s) red[t] += red[t+s];
    __syncthreads();
  }
  float mu = red[0] / 240.f;
  __syncthreads();
  float dv = (t<240) ? (val-mu) : 0.f;
  red[t] = dv*dv;
  __syncthreads();
  #pragma unroll
  for (int s=128; s>=1; s>>=1){
    if (t < s) red[t] += red[t+s];
    __syncthreads();
  }
  float rstd = rsqrtf(red[0]/240.f + 1e-5f);
  if (t < 240){
    float r = (val-mu)*rstd*g[t] + b2[t];
    if (*flag) ((bf16*)outv)[n*240+t] = __float2bfloat16(r);
    else       ((float*)outv)[n*240+t] = r;
  }
}

// ---------------- launcher ----------------
extern "C" void kernel_launch(void* const* d_in, const int* in_sizes, int n_in,
                              void* d_out, int out_size, void* d_ws, size_t ws_size,
                              hipStream_t stream){
  (void)in_sizes; (void)n_in; (void)out_size; (void)ws_size;
  char* ws = (char*)d_ws;
  size_t cur = 0;
  auto carve = [&](size_t bytes)->char*{ char* pp = ws+cur; cur += (bytes+255)&~(size_t)255; return pp; };
  int*   flag = (int*)  carve(4);
  float* cg   = (float*)carve(363*4);
  float* wf   = (float*)carve(100992ull*4);     // all small params (wm3/bm3 excluded)
  ushort* wm3h= (ushort*)carve(5349888ull*2);   // wm3 (5308416) + bm3 (41472) in bf16
  float* xA   = (float*)carve(160*240*4);
  float* xB   = (float*)carve(160*240*4);
  float* agg  = (float*)carve(160*240*4);
  float* deg  = (float*)carve(160*4);
  int*   nlist= (int*)  carve(160*64*4);
  int*   ndeg2= (int*)  carve(160*4);
  float* ef   = (float*)carve(6400*4);
  float* erbf = (float*)carve(6400*16*4);
  float* esh  = (float*)carve(6400*9*4);
  float* h2   = (float*)carve((size_t)6401*129*4);   // +1 dummy zero row
  float* Yb   = (float*)carve((size_t)6401*1184*4);  // +1 dummy row (never needs zeroing)

  static const int cnts[15]   = {480,6464,5184,6144,384,49152,384,12288,3072,768,12288,3072,768,240,240};
  static const int srcIdx[15] = {1,3,4,5,6,7,8,11,12,13,14,15,16,17,18};
  CvtTab tab; int off = 0; float* fp[15];
  for (int s=0;s<15;s++){ tab.src[s] = d_in[srcIdx[s]]; tab.off[s] = off; tab.cnt[s] = cnts[s]; fp[s] = wf + off; off += cnts[s]; }
  tab.total = off;
  float *posf=fp[0], *zembf=fp[1], *w_inf=fp[2], *wm1f=fp[3], *bm1f=fp[4], *wm2f=fp[5], *bm2f=fp[6],
        *ws0f=fp[7], *ws1f=fp[8], *ws2f=fp[9], *wo0f=fp[10], *wo1f=fp[11], *wo2f=fp[12],
        *lngf=fp[13], *lnbf=fp[14];
  ushort* bm3h = wm3h + 5308416;

  k_flag<<<1,64,0,stream>>>((const unsigned int*)d_in[17], flag);
  k_convert<<<(tab.total+255)/256,256,0,stream>>>(tab, flag, wf);
  k_wcvt2<<<(5349888+255)/256,256,0,stream>>>(d_in[9], d_in[10], flag, wm3h);
  k_cg<<<1,384,0,stream>>>(cg);
  k0a<<<25,256,0,stream>>>(posf, ef, erbf, esh);
  k0b<<<160,64,0,stream>>>((const int*)d_in[0], posf, zembf, w_inf, ef, xA, deg, nlist, ndeg2, h2);

  float* xcur = xA; float* xnxt = xB;
  for (int t=0;t<3;t++){
    k12<<<6400,128,0,stream>>>(erbf, wm1f + t*2048, bm1f + t*128, wm2f + t*16384, bm2f + t*128,
                               ef, xcur, esh, cg, h2, Yb, agg);
    const ushort* wm3t = wm3h + (size_t)t*1769472;
    const ushort* bm3t = bm3h + (size_t)t*13824;
    k34<<<dim3(160,8,5),256,0,stream>>>(h2, Yb, wm3t, bm3t, nlist, ndeg2, agg);
    if (t < 2){
      k5_update<<<160,256,0,stream>>>(xcur, agg, deg, ws0f+t*4096, ws1f+t*1024, ws2f+t*256,
                                      wo0f+t*4096, wo1f+t*1024, wo2f+t*256, xnxt);
    } else {
      k5_ln<<<160,256,0,stream>>>(xcur, agg, deg, ws0f+t*4096, ws1f+t*1024, ws2f+t*256,
                                  wo0f+t*4096, wo1f+t*1024, wo2f+t*256, lngf, lnbf, flag, d_out);
    }
    float* tmp = xcur; xcur = xnxt; xnxt = tmp;
  }
}

// Round 18
// 714.392 us; speedup vs baseline: 1.0870x; 1.0870x over previous
//
#include <hip/hip_runtime.h>
#include <hip/hip_bf16.h>

typedef __hip_bfloat16 bf16;

#define PLW 320  // max uk-phase width

// ---------------- constant tables ----------------
// Y layout uses permuted path order [0,1,3,2,4,5,6,7,8,9,10] so the 5
// fully load-balanced (un=4) w-con phases are contiguous in Y.
__constant__ int d_ybnd[12] = {0,64,96,288,304,400,496,544,864,1024,1104,1184}; // slot bounds
__constant__ int d_yperm[11]= {0,1,3,2,4,5,6,7,8,9,10};                         // slot -> path
__constant__ int d_pl1[11]  = {0,1,2,0,1,1,2,0,1,2,2};
__constant__ int d_pl2[11]  = {0,1,2,1,0,2,1,2,1,0,2};
__constant__ int d_plo[11]  = {0,0,0,1,1,1,1,2,2,2,2};
__constant__ int d_cgoffE[12]= {0,1,10,35,44,53,98,143,168,213,238,363};
__constant__ int d_woff[11] = {0,4096,6144,7168,9216,10240,11264,11776,12800,13312,13568};
__constant__ int d_dims[3]  = {1,3,5};
__constant__ int d_muls[3]  = {64,32,16};
__constant__ int d_segb[3]  = {0,64,160};
__constant__ int d_shb[3]   = {0,1,4};
__constant__ int d_phb5[6]  = {0,64,288,544,864,1184};  // 5 phase bases (path-aligned in permuted Y)
__constant__ int d_obeg5[5] = {0,0,0,160,160};          // per-phase agg output range
__constant__ int d_oend5[5] = {64,160,160,240,240};

// ---------------- dtype flag + input conversion ----------------
__global__ void k_flag(const unsigned int* w, int* flag){
  if (threadIdx.x==0 && blockIdx.x==0) *flag = (w[0] == 0x3F800000u) ? 0 : 1;
}

struct CvtTab { const void* src[15]; int off[15]; int cnt[15]; int total; };

__global__ void __launch_bounds__(256) k_convert(CvtTab tab, const int* __restrict__ flag,
                                                 float* __restrict__ wf){
  int f = *flag;
  int idx = blockIdx.x*256 + threadIdx.x;
  if (idx >= tab.total) return;
  int a = idx, s = 0;
  while (a >= tab.cnt[s]){ a -= tab.cnt[s]; s++; }
  float v;
  if (f) v = __bfloat162float(((const bf16*)tab.src[s])[a]);
  else   v = ((const float*)tab.src[s])[a];
  wf[tab.off[s] + a] = v;
}

// wm3/bm3 -> bf16 directly from raw inputs (bf16 input: pure copy; f32: convert)
__global__ void __launch_bounds__(256) k_wcvt2(const void* __restrict__ wm3raw,
                  const void* __restrict__ bm3raw, const int* __restrict__ flag,
                  ushort* __restrict__ dst){
  int i = blockIdx.x*256 + threadIdx.x;
  if (i >= 5349888) return;
  int f = *flag;
  if (i < 5308416){
    if (f) dst[i] = ((const ushort*)wm3raw)[i];
    else   dst[i] = (ushort)(__hip_bfloat16_raw(__float2bfloat16(((const float*)wm3raw)[i])).x);
  } else {
    int a = i - 5308416;
    if (f) dst[i] = ((const ushort*)bm3raw)[a];
    else   dst[i] = (ushort)(__hip_bfloat16_raw(__float2bfloat16(((const float*)bm3raw)[a])).x);
  }
}

// ---------------- CG tensors (parallel: 1 thread per entry, same f64 math) ----------------
__device__ double dfact_d(int n){ double r=1.0; while(n>1){ r*=n; n-=2; } return r; }
__device__ double mavg_d(int a,int b,int c){
  if ((a&1)||(b&1)||(c&1)) return 0.0;
  return dfact_d(a-1)*dfact_d(b-1)*dfact_d(c-1)/dfact_d(a+b+c+1);
}

__global__ void __launch_bounds__(384) k_cg(float* cg){
  __shared__ double Gs[363];
  __shared__ double scl[11];
  int t = threadIdx.x;
  const double s3 = sqrt(3.0), s5 = sqrt(5.0), s15 = sqrt(15.0);
  int cnt[3][5]; double cf[3][5][2]; int ex[3][5][2][3];
  for (int l=0;l<3;l++) for (int m=0;m<5;m++){
    cnt[l][m]=0;
    for (int q=0;q<2;q++){ cf[l][m][q]=0.0; for(int a=0;a<3;a++) ex[l][m][q][a]=0; }
  }
  cnt[0][0]=1; cf[0][0][0]=1.0;
  cnt[1][0]=1; cf[1][0][0]=s3; ex[1][0][0][0]=1;
  cnt[1][1]=1; cf[1][1][0]=s3; ex[1][1][0][1]=1;
  cnt[1][2]=1; cf[1][2][0]=s3; ex[1][2][0][2]=1;
  cnt[2][0]=1; cf[2][0][0]=s15; ex[2][0][0][0]=1; ex[2][0][0][1]=1;
  cnt[2][1]=1; cf[2][1][0]=s15; ex[2][1][0][1]=1; ex[2][1][0][2]=1;
  cnt[2][2]=2; cf[2][2][0]=1.5*s5; ex[2][2][0][2]=2; cf[2][2][1]=-0.5*s5;
  cnt[2][3]=1; cf[2][3][0]=s15; ex[2][3][0][0]=1; ex[2][3][0][2]=1;
  cnt[2][4]=2; cf[2][4][0]=0.5*s15; ex[2][4][0][0]=2; cf[2][4][1]=-0.5*s15; ex[2][4][1][1]=2;
  if (t < 363){
    int p=0; while (t >= d_cgoffE[p+1]) p++;
    int l1=d_pl1[p], l2=d_pl2[p], l3=d_plo[p];
    int n2=2*l2+1, n3=2*l3+1;
    int loc = t - d_cgoffE[p];
    int k = loc % n3; int ij = loc / n3; int j = ij % n2; int i = ij / n2;
    double s=0.0;
    for (int t1=0;t1<cnt[l1][i];t1++)
      for (int t2=0;t2<cnt[l2][j];t2++)
        for (int t3=0;t3<cnt[l3][k];t3++){
          int a=ex[l1][i][t1][0]+ex[l2][j][t2][0]+ex[l3][k][t3][0];
          int b=ex[l1][i][t1][1]+ex[l2][j][t2][1]+ex[l3][k][t3][1];
          int c=ex[l1][i][t1][2]+ex[l2][j][t2][2]+ex[l3][k][t3][2];
          s += cf[l1][i][t1]*cf[l2][j][t2]*cf[l3][k][t3]*mavg_d(a,b,c);
        }
    Gs[t] = s;
  }
  __syncthreads();
  if (t < 11){
    double ssq=0.0;
    for (int q=d_cgoffE[t]; q<d_cgoffE[t+1]; q++) ssq += Gs[q]*Gs[q];
    scl[t] = sqrt((double)(2*d_plo[t]+1)/ssq);
  }
  __syncthreads();
  if (t < 363){
    int p=0; while (t >= d_cgoffE[p+1]) p++;
    cg[t] = (float)(Gs[t]*scl[p]);
  }
}

// ---------------- edge geometry ----------------
__global__ void __launch_bounds__(256) k0a(const float* __restrict__ posf, float* __restrict__ ef,
                   float* __restrict__ erbf, float* __restrict__ esh){
  int e = blockIdx.x*256 + threadIdx.x;
  if (e >= 6400) return;
  int b = e/1600; int r1 = e - b*1600; int i = r1/40; int j = r1 - i*40;
  float dx = posf[(b*40+j)*3+0] - posf[(b*40+i)*3+0];
  float dy = posf[(b*40+j)*3+1] - posf[(b*40+i)*3+1];
  float dz = posf[(b*40+j)*3+2] - posf[(b*40+i)*3+2];
  float sq = dx*dx+dy*dy+dz*dz;
  float em = (sq <= 36.f && sq > 1e-16f) ? 1.f : 0.f;
  ef[e] = em;
  float elen = (sq > 1e-12f) ? sqrtf(sq) : 0.f;
  float inv = 1.f/fmaxf(elen, 1e-8f);
  float x = dx*inv, y = dy*inv, z = dz*inv;
  float rc = fminf(elen, 6.f);
  #pragma unroll
  for (int k=0;k<16;k++){ float d = rc - 0.4f*(float)k; erbf[e*16+k] = expf(-6.25f*d*d); }
  const float S3=1.7320508075688772f, S5=2.23606797749979f, S15=3.872983346207417f;
  float* sh = esh + e*9;
  sh[0]=1.f; sh[1]=S3*x; sh[2]=S3*y; sh[3]=S3*z;
  sh[4]=S15*x*y; sh[5]=S15*y*z; sh[6]=0.5f*S5*(3.f*z*z-1.f); sh[7]=S15*x*z; sh[8]=0.5f*S15*(x*x-y*y);
}

// ---------------- node init + neighbor edge-list (deterministic ballot order, padded to even) ----------------
__global__ void __launch_bounds__(64) k0b(const int* __restrict__ z, const float* __restrict__ posf,
                  const float* __restrict__ zembf, const float* __restrict__ w_inf,
                  const float* __restrict__ ef,
                  float* __restrict__ x, float* __restrict__ deg,
                  int* __restrict__ nlist, int* __restrict__ ndeg2,
                  float* __restrict__ h2){
  int n = blockIdx.x; int lane = threadIdx.x;
  int b = n/40; int i = n - b*40;
  __shared__ float sc[81];
  float dx = posf[n*3+0]-posf[b*120+0];
  float dy = posf[n*3+1]-posf[b*120+1];
  float dz = posf[n*3+2]-posf[b*120+2];
  float sq = dx*dx+dy*dy+dz*dz;
  float r = (sq>1e-12f)? sqrtf(sq) : 0.f;
  sc[lane] = zembf[z[n]*64+lane];
  if (lane == 0) sc[64] = (i==0)?1.f:0.f;
  if (lane < 16){ float d = fminf(r,6.f)-0.4f*(float)lane; sc[65+lane] = expf(-6.25f*d*d); }
  // edge from src=lane to dst=i: e = b*1600 + lane*40 + i
  bool live = (lane < 40) && (ef[b*1600 + lane*40 + i] > 0.f);
  unsigned long long m = __ballot(live);
  if (live){
    int pos = __popcll(m & ((1ull<<lane)-1ull));
    nlist[n*64 + pos] = b*1600 + lane*40 + i;
  }
  if (lane == 0){
    int dg = __popcll(m);
    int dgp = (dg+1) & ~1;                 // pad to even with dummy edge 6400
    if (dg & 1) nlist[n*64 + dg] = 6400;
    ndeg2[n] = dgp;
    deg[n] = fmaxf((float)dg, 1.f);
  }
  if (n == 0){                             // zero dummy h2 row once per launch
    for (int c = lane; c < 129; c += 64) h2[6400*129 + c] = 0.f;
  }
  __syncthreads();
  float a = 0.f;
  for (int s=0;s<81;s++) a += sc[s]*w_inf[s*64+lane];
  x[n*240+lane] = a/9.f;
  for (int c = 64+lane; c < 240; c += 64) x[n*240+c] = 0.f;
}

// ---------------- fused edge MLP + Y (1 edge/block; also zeroes agg) ----------------
__global__ void __launch_bounds__(128) k12(const float* __restrict__ erbf, const float* __restrict__ wm1,
                   const float* __restrict__ bm1, const float* __restrict__ wm2,
                   const float* __restrict__ bm2, const float* __restrict__ ef,
                   const float* __restrict__ x, const float* __restrict__ esh,
                   const float* __restrict__ cg,
                   float* __restrict__ h2, float* __restrict__ Y, float* __restrict__ agg){
  int e = blockIdx.x;
  int t = threadIdx.x;
  if (e < 160){                            // zero agg for this layer (before any early exit)
    agg[e*240 + t] = 0.f;
    if (t < 112) agg[e*240 + 128 + t] = 0.f;
  }
  if (ef[e] == 0.f) return;                // uniform branch: whole block exits
  __shared__ float h1L[128];
  __shared__ float xL[240];
  __shared__ float cgL[363];
  // ---- edge MLP ----
  float a = bm1[t];
  #pragma unroll
  for (int k=0;k<16;k++) a += erbf[e*16+k]*wm1[k*128+t];
  h1L[t] = a/(1.f+expf(-a));
  int src = e/40;
  for (int c = t; c < 240; c += 128) xL[c] = x[src*240+c];
  for (int c = t; c < 363; c += 128) cgL[c] = cg[c];
  __syncthreads();
  float a2 = bm2[t];
  #pragma unroll 8
  for (int k=0;k<128;k++) a2 += h1L[k]*wm2[k*128+t];
  float s = a2/(1.f+expf(-a2));
  h2[e*129+t] = s;
  if (t==0) h2[e*129+128] = 1.f;
  // ---- Y (permuted layout) ----
  float sh[9];
  #pragma unroll
  for (int q=0;q<9;q++) sh[q] = esh[e*9+q];
  int s2 = 0;
  for (int uk = t; uk < 1184; uk += 128){
    while (uk >= d_ybnd[s2+1]) s2++;
    int p = d_yperm[s2];
    int l1 = d_pl1[p], l2 = d_pl2[p], lo = d_plo[p];
    int dim1 = d_dims[l1], dim2 = d_dims[l2], dimo = d_dims[lo];
    int loc = uk - d_ybnd[s2];
    int u = loc/dimo; int k = loc - u*dimo;
    const float* C = cgL + d_cgoffE[p];
    int xb = d_segb[l1] + u*dim1;
    int shb = d_shb[l2];
    float acc = 0.f;
    for (int i2=0;i2<dim1;i2++){
      float Dik = 0.f;
      for (int j2=0;j2<dim2;j2++) Dik += sh[shb+j2]*C[(i2*dim2+j2)*dimo + k];
      acc += xL[xb+i2]*Dik;
    }
    Y[(size_t)e*1184+uk] = acc;
  }
}

// ---------------- w-contraction: bf16 via uint2, 4 w per thread, un=4 (round-15 exact) ----------------
template<int DD>
__device__ __forceinline__ void wcon(const ushort* __restrict__ wm3t, const ushort* __restrict__ bm3t,
    int h0, bool bias, const float* PLb, int wc, int Wp, int u0, int un,
    float* aggL, int outb){
  float acc[4*DD];
  #pragma unroll
  for (int q=0;q<4*DD;q++) acc[q]=0.f;
  for (int h=0; h<16; h++){
    const ushort* wrow = wm3t + (size_t)(h0+h)*13824 + wc;
    const float* pr = PLb + h*PLW;
    #pragma unroll 4
    for (int u=u0; u<u0+un; u++){
      uint2 wv = *(const uint2*)(wrow + u*Wp);
      const float* pp = pr + u*DD;
      #pragma unroll
      for (int k=0;k<DD;k++){
        float pv = pp[k];
        acc[0*DD+k] += __uint_as_float(wv.x << 16)*pv;
        acc[1*DD+k] += __uint_as_float(wv.x & 0xFFFF0000u)*pv;
        acc[2*DD+k] += __uint_as_float(wv.y << 16)*pv;
        acc[3*DD+k] += __uint_as_float(wv.y & 0xFFFF0000u)*pv;
      }
    }
  }
  if (bias){
    const ushort* wrow = bm3t + wc;
    const float* pr = PLb + 16*PLW;
    #pragma unroll 4
    for (int u=u0; u<u0+un; u++){
      uint2 wv = *(const uint2*)(wrow + u*Wp);
      const float* pp = pr + u*DD;
      #pragma unroll
      for (int k=0;k<DD;k++){
        float pv = pp[k];
        acc[0*DD+k] += __uint_as_float(wv.x << 16)*pv;
        acc[1*DD+k] += __uint_as_float(wv.x & 0xFFFF0000u)*pv;
        acc[2*DD+k] += __uint_as_float(wv.y << 16)*pv;
        acc[3*DD+k] += __uint_as_float(wv.y & 0xFFFF0000u)*pv;
      }
    }
  }
  #pragma unroll
  for (int j=0;j<4;j++)
    #pragma unroll
    for (int k=0;k<DD;k++)
      atomicAdd(&aggL[outb + j*DD + k], acc[j*DD+k]);
}

// ---------------- fused TP: P-build (edge-list, x2 unroll) + w-contraction (round-15 exact) ----------------
// grid (160, 8, 5): x = node n (fastest), y = h-chunk hc of 16 [+bias row hc==7], z = phase.
__global__ void __launch_bounds__(256) k34(const float* __restrict__ h2,
        const float* __restrict__ Y, const ushort* __restrict__ wm3t,
        const ushort* __restrict__ bm3t, const int* __restrict__ nlist,
        const int* __restrict__ ndeg2, float* __restrict__ agg){
  __shared__ float PL[17*PLW];
  __shared__ float aggL[240];
  int n = blockIdx.x, hc = blockIdx.y, ph = blockIdx.z;
  int t = threadIdx.x;
  int h0 = hc*16;
  bool bias = (hc==7);
  const int* nl = nlist + n*64;
  int dg2 = ndeg2[n];
  for (int q=t; q<240; q+=256) aggL[q]=0.f;

  int base = d_phb5[ph], width = d_phb5[ph+1] - base;
  // ---- P-build: PL[h, c] = sum_q h2[e_q, h0+h] * Y[e_q, base+c], 2 edges in flight ----
  for (int cc = t; cc < width; cc += 256){
    float pacc[17];
    #pragma unroll
    for (int h=0;h<17;h++) pacc[h]=0.f;
    for (int q=0; q<dg2; q+=2){
      int e0 = nl[q], e1 = nl[q+1];                       // wave-uniform s_loads
      float yv0 = Y[(size_t)e0*1184 + base + cc];
      float yv1 = Y[(size_t)e1*1184 + base + cc];
      const float* hh0 = h2 + e0*129 + h0;
      const float* hh1 = h2 + e1*129 + h0;
      #pragma unroll
      for (int h=0;h<17;h++) pacc[h] += yv0*hh0[h] + yv1*hh1[h];
    }
    #pragma unroll
    for (int h=0;h<17;h++) PL[h*PLW+cc] = pacc[h];
  }
  __syncthreads();
  // ---- w-contraction: every thread un=4 (64-load chain) ----
  if (ph==0){        // {p0}
    { int w4=t&15; int uc=t>>4;          wcon<1>(wm3t,bm3t,h0,bias, PL+0,   d_woff[0]+w4*4, 64, uc*4, 4, aggL, 0+w4*4); }
  } else if (ph==1){ // {p1 yloc 0, p3 yloc 32}
    if      (t<128){ int w4=t&15; int uc=t>>4;            wcon<1>(wm3t,bm3t,h0,bias, PL+0,  d_woff[1]+w4*4, 64, uc*4, 4, aggL, 0+w4*4); }
    else           { int tt=t-128; int w4=tt&7; int uc=tt>>3; wcon<3>(wm3t,bm3t,h0,bias, PL+32, d_woff[3]+w4*4, 32, uc*4, 4, aggL, 64+w4*12); }
  } else if (ph==2){ // {p2 yloc 0, p4 yloc 16, p5 yloc 112, p6 yloc 208}
    if      (t<64) { int w4=t&15; int uc=t>>4;            wcon<1>(wm3t,bm3t,h0,bias, PL+0,   d_woff[2]+w4*4, 64, uc*4, 4, aggL, 0+w4*4); }
    else if (t<128){ int tt=t-64;  int w4=tt&7; int uc=tt>>3; wcon<3>(wm3t,bm3t,h0,bias, PL+16,  d_woff[4]+w4*4, 32, uc*4, 4, aggL, 64+w4*12); }
    else if (t<192){ int tt=t-128; int w4=tt&7; int uc=tt>>3; wcon<3>(wm3t,bm3t,h0,bias, PL+112, d_woff[5]+w4*4, 32, uc*4, 4, aggL, 64+w4*12); }
    else if (t<224){ int tt=t-192; int w4=tt&7; int uc=tt>>3; wcon<3>(wm3t,bm3t,h0,bias, PL+208, d_woff[6]+w4*4, 32, uc*4, 4, aggL, 64+w4*12); }
  } else if (ph==3){ // {p7}
    if (t<64)      { int w4=t&3; int uc=t>>2;             wcon<5>(wm3t,bm3t,h0,bias, PL+0,   d_woff[7]+w4*4, 16, uc*4, 4, aggL, 160+w4*20); }
  } else {           // {p8 yloc 0, p9 yloc 160, p10 yloc 240}
    if      (t<32) { int w4=t&3; int uc=t>>2;             wcon<5>(wm3t,bm3t,h0,bias, PL+0,   d_woff[8]+w4*4, 16, uc*4, 4, aggL, 160+w4*20); }
    else if (t<48) { int tt=t-32; int w4=tt&3; int uc=tt>>2; wcon<5>(wm3t,bm3t,h0,bias, PL+160, d_woff[9]+w4*4, 16, uc*4, 4, aggL, 160+w4*20); }
    else if (t<64) { int tt=t-48; int w4=tt&3; int uc=tt>>2; wcon<5>(wm3t,bm3t,h0,bias, PL+240, d_woff[10]+w4*4,16, uc*4, 4, aggL, 160+w4*20); }
  }
  __syncthreads();
  int beg = d_obeg5[ph], end = d_oend5[ph];
  for (int q = beg + t; q < end; q += 256) atomicAdd(&agg[n*240 + q], aggL[q]);
}

// ---------------- node update: x += irlin(x,ws) + irlin(agg_scaled,wo) ----------------
__global__ void __launch_bounds__(256) k5_update(const float* __restrict__ x, const float* __restrict__ agg,
    const float* __restrict__ deg,
    const float* __restrict__ ws0,const float* __restrict__ ws1,const float* __restrict__ ws2,
    const float* __restrict__ wo0,const float* __restrict__ wo1,const float* __restrict__ wo2,
    float* __restrict__ xn){
  int n = blockIdx.x; int t = threadIdx.x;
  __shared__ float xr[240], ar[240];
  float dg = deg[n];
  if (t < 240){
    float fan = (t<64)?112.f:((t<160)?144.f:128.f);
    xr[t] = x[n*240+t];
    ar[t] = agg[n*240+t]/(sqrtf(fan)*dg);
  }
  __syncthreads();
  if (t < 240){
    int lo  = (t<64)?0:((t<160)?1:2);
    int base= (lo==0)?0:((lo==1)?64:160);
    int mul = (lo==0)?64:((lo==1)?32:16);
    int d   = (lo==0)?1:((lo==1)?3:5);
    int loc = t - base; int wi = loc/d; int dd = loc - wi*d;
    const float* Ws = (lo==0)?ws0:((lo==1)?ws1:ws2);
    const float* Wo = (lo==0)?wo0:((lo==1)?wo1:wo2);
    float s1=0.f, s2=0.f;
    for (int u=0; u<mul; u++){
      s1 += xr[base+u*d+dd]*Ws[u*mul+wi];
      s2 += ar[base+u*d+dd]*Wo[u*mul+wi];
    }
    xn[n*240+t] = xr[t] + (s1+s2)*rsqrtf((float)mul);
  }
}

// ---------------- last-layer node update + fused LayerNorm -> d_out ----------------
__global__ void __launch_bounds__(256) k5_ln(const float* __restrict__ x, const float* __restrict__ agg,
    const float* __restrict__ deg,
    const float* __restrict__ ws0,const float* __restrict__ ws1,const float* __restrict__ ws2,
    const float* __restrict__ wo0,const float* __restrict__ wo1,const float* __restrict__ wo2,
    const float* __restrict__ g, const float* __restrict__ b2,
    const int* __restrict__ flag, void* outv){
  int n = blockIdx.x; int t = threadIdx.x;
  __shared__ float xr[240], ar[240];
  __shared__ float red[256];
  float dg = deg[n];
  if (t < 240){
    float fan = (t<64)?112.f:((t<160)?144.f:128.f);
    xr[t] = x[n*240+t];
    ar[t] = agg[n*240+t]/(sqrtf(fan)*dg);
  }
  __syncthreads();
  float val = 0.f;
  if (t < 240){
    int lo  = (t<64)?0:((t<160)?1:2);
    int base= (lo==0)?0:((lo==1)?64:160);
    int mul = (lo==0)?64:((lo==1)?32:16);
    int d   = (lo==0)?1:((lo==1)?3:5);
    int loc = t - base; int wi = loc/d; int dd = loc - wi*d;
    const float* Ws = (lo==0)?ws0:((lo==1)?ws1:ws2);
    const float* Wo = (lo==0)?wo0:((lo==1)?wo1:wo2);
    float s1=0.f, s2=0.f;
    for (int u=0; u<mul; u++){
      s1 += xr[base+u*d+dd]*Ws[u*mul+wi];
      s2 += ar[base+u*d+dd]*Wo[u*mul+wi];
    }
    val = xr[t] + (s1+s2)*rsqrtf((float)mul);
  }
  red[t] = (t<240) ? val : 0.f;
  __syncthreads();
  #pragma unroll
  for (int s=128; s>=1; s>>=1){
    if (t < s) red[t] += red[t+s];
    __syncthreads();
  }
  float mu = red[0] / 240.f;
  __syncthreads();
  float dv = (t<240) ? (val-mu) : 0.f;
  red[t] = dv*dv;
  __syncthreads();
  #pragma unroll
  for (int s=128; s>=1; s>>=1){
    if (t < s) red[t] += red[t+s];
    __syncthreads();
  }
  float rstd = rsqrtf(red[0]/240.f + 1e-5f);
  if (t < 240){
    float r = (val-mu)*rstd*g[t] + b2[t];
    if (*flag) ((bf16*)outv)[n*240+t] = __float2bfloat16(r);
    else       ((float*)outv)[n*240+t] = r;
  }
}

// ---------------- launcher ----------------
extern "C" void kernel_launch(void* const* d_in, const int* in_sizes, int n_in,
                              void* d_out, int out_size, void* d_ws, size_t ws_size,
                              hipStream_t stream){
  (void)in_sizes; (void)n_in; (void)out_size; (void)ws_size;
  char* ws = (char*)d_ws;
  size_t cur = 0;
  auto carve = [&](size_t bytes)->char*{ char* pp = ws+cur; cur += (bytes+255)&~(size_t)255; return pp; };
  int*   flag = (int*)  carve(4);
  float* cg   = (float*)carve(363*4);
  float* wf   = (float*)carve(100992ull*4);     // all small params (wm3/bm3 excluded)
  ushort* wm3h= (ushort*)carve(5349888ull*2);   // wm3 (5308416) + bm3 (41472) in bf16
  float* xA   = (float*)carve(160*240*4);
  float* xB   = (float*)carve(160*240*4);
  float* agg  = (float*)carve(160*240*4);
  float* deg  = (float*)carve(160*4);
  int*   nlist= (int*)  carve(160*64*4);
  int*   ndeg2= (int*)  carve(160*4);
  float* ef   = (float*)carve(6400*4);
  float* erbf = (float*)carve(6400*16*4);
  float* esh  = (float*)carve(6400*9*4);
  float* h2   = (float*)carve((size_t)6401*129*4);   // +1 dummy zero row
  float* Yb   = (float*)carve((size_t)6401*1184*4);  // +1 dummy row (never needs zeroing)

  static const int cnts[15]   = {480,6464,5184,6144,384,49152,384,12288,3072,768,12288,3072,768,240,240};
  static const int srcIdx[15] = {1,3,4,5,6,7,8,11,12,13,14,15,16,17,18};
  CvtTab tab; int off = 0; float* fp[15];
  for (int s=0;s<15;s++){ tab.src[s] = d_in[srcIdx[s]]; tab.off[s] = off; tab.cnt[s] = cnts[s]; fp[s] = wf + off; off += cnts[s]; }
  tab.total = off;
  float *posf=fp[0], *zembf=fp[1], *w_inf=fp[2], *wm1f=fp[3], *bm1f=fp[4], *wm2f=fp[5], *bm2f=fp[6],
        *ws0f=fp[7], *ws1f=fp[8], *ws2f=fp[9], *wo0f=fp[10], *wo1f=fp[11], *wo2f=fp[12],
        *lngf=fp[13], *lnbf=fp[14];
  ushort* bm3h = wm3h + 5308416;

  k_flag<<<1,64,0,stream>>>((const unsigned int*)d_in[17], flag);
  k_convert<<<(tab.total+255)/256,256,0,stream>>>(tab, flag, wf);
  k_wcvt2<<<(5349888+255)/256,256,0,stream>>>(d_in[9], d_in[10], flag, wm3h);
  k_cg<<<1,384,0,stream>>>(cg);
  k0a<<<25,256,0,stream>>>(posf, ef, erbf, esh);
  k0b<<<160,64,0,stream>>>((const int*)d_in[0], posf, zembf, w_inf, ef, xA, deg, nlist, ndeg2, h2);

  float* xcur = xA; float* xnxt = xB;
  for (int t=0;t<3;t++){
    k12<<<6400,128,0,stream>>>(erbf, wm1f + t*2048, bm1f + t*128, wm2f + t*16384, bm2f + t*128,
                               ef, xcur, esh, cg, h2, Yb, agg);
    const ushort* wm3t = wm3h + (size_t)t*1769472;
    const ushort* bm3t = bm3h + (size_t)t*13824;
    k34<<<dim3(160,8,5),256,0,stream>>>(h2, Yb, wm3t, bm3t, nlist, ndeg2, agg);
    if (t < 2){
      k5_update<<<160,256,0,stream>>>(xcur, agg, deg, ws0f+t*4096, ws1f+t*1024, ws2f+t*256,
                                      wo0f+t*4096, wo1f+t*1024, wo2f+t*256, xnxt);
    } else {
      k5_ln<<<160,256,0,stream>>>(xcur, agg, deg, ws0f+t*4096, ws1f+t*1024, ws2f+t*256,
                                  wo0f+t*4096, wo1f+t*1024, wo2f+t*256, lngf, lnbf, flag, d_out);
    }
    float* tmp = xcur; xcur = xnxt; xnxt = tmp;
  }
}

// Round 19
// 707.342 us; speedup vs baseline: 1.0978x; 1.0100x over previous
//
#include <hip/hip_runtime.h>
#include <hip/hip_bf16.h>

typedef __hip_bfloat16 bf16;

#define PLW 320  // max uk-phase width

// ---------------- constant tables ----------------
// Y layout uses permuted path order [0,1,3,2,4,5,6,7,8,9,10] so the 5
// fully load-balanced (un=4) w-con phases are contiguous in Y.
__constant__ int d_ybnd[12] = {0,64,96,288,304,400,496,544,864,1024,1104,1184}; // slot bounds
__constant__ int d_yperm[11]= {0,1,3,2,4,5,6,7,8,9,10};                         // slot -> path
__constant__ int d_pl1[11]  = {0,1,2,0,1,1,2,0,1,2,2};
__constant__ int d_pl2[11]  = {0,1,2,1,0,2,1,2,1,0,2};
__constant__ int d_plo[11]  = {0,0,0,1,1,1,1,2,2,2,2};
__constant__ int d_cgoffE[12]= {0,1,10,35,44,53,98,143,168,213,238,363};
__constant__ int d_woff[11] = {0,4096,6144,7168,9216,10240,11264,11776,12800,13312,13568};
__constant__ int d_dims[3]  = {1,3,5};
__constant__ int d_muls[3]  = {64,32,16};
__constant__ int d_segb[3]  = {0,64,160};
__constant__ int d_shb[3]   = {0,1,4};
__constant__ int d_phb5[6]  = {0,64,288,544,864,1184};  // 5 phase bases (path-aligned in permuted Y)
__constant__ int d_obeg5[5] = {0,0,0,160,160};          // per-phase agg output range
__constant__ int d_oend5[5] = {64,160,160,240,240};

// ---------------- dtype flag + input conversion ----------------
__global__ void k_flag(const unsigned int* w, int* flag){
  if (threadIdx.x==0 && blockIdx.x==0) *flag = (w[0] == 0x3F800000u) ? 0 : 1;
}

struct CvtTab { const void* src[15]; int off[15]; int cnt[15]; int total; };

__global__ void __launch_bounds__(256) k_convert(CvtTab tab, const int* __restrict__ flag,
                                                 float* __restrict__ wf){
  int f = *flag;
  int idx = blockIdx.x*256 + threadIdx.x;
  if (idx >= tab.total) return;
  int a = idx, s = 0;
  while (a >= tab.cnt[s]){ a -= tab.cnt[s]; s++; }
  float v;
  if (f) v = __bfloat162float(((const bf16*)tab.src[s])[a]);
  else   v = ((const float*)tab.src[s])[a];
  wf[tab.off[s] + a] = v;
}

// wm3/bm3 -> bf16 directly from raw inputs (bf16 input: pure copy; f32: convert)
__global__ void __launch_bounds__(256) k_wcvt2(const void* __restrict__ wm3raw,
                  const void* __restrict__ bm3raw, const int* __restrict__ flag,
                  ushort* __restrict__ dst){
  int i = blockIdx.x*256 + threadIdx.x;
  if (i >= 5349888) return;
  int f = *flag;
  if (i < 5308416){
    if (f) dst[i] = ((const ushort*)wm3raw)[i];
    else   dst[i] = (ushort)(__hip_bfloat16_raw(__float2bfloat16(((const float*)wm3raw)[i])).x);
  } else {
    int a = i - 5308416;
    if (f) dst[i] = ((const ushort*)bm3raw)[a];
    else   dst[i] = (ushort)(__hip_bfloat16_raw(__float2bfloat16(((const float*)bm3raw)[a])).x);
  }
}

// ---------------- CG tensors (parallel: 1 thread per entry, same f64 math) ----------------
__device__ double dfact_d(int n){ double r=1.0; while(n>1){ r*=n; n-=2; } return r; }
__device__ double mavg_d(int a,int b,int c){
  if ((a&1)||(b&1)||(c&1)) return 0.0;
  return dfact_d(a-1)*dfact_d(b-1)*dfact_d(c-1)/dfact_d(a+b+c+1);
}

__global__ void __launch_bounds__(384) k_cg(float* cg){
  __shared__ double Gs[363];
  __shared__ double scl[11];
  int t = threadIdx.x;
  const double s3 = sqrt(3.0), s5 = sqrt(5.0), s15 = sqrt(15.0);
  int cnt[3][5]; double cf[3][5][2]; int ex[3][5][2][3];
  for (int l=0;l<3;l++) for (int m=0;m<5;m++){
    cnt[l][m]=0;
    for (int q=0;q<2;q++){ cf[l][m][q]=0.0; for(int a=0;a<3;a++) ex[l][m][q][a]=0; }
  }
  cnt[0][0]=1; cf[0][0][0]=1.0;
  cnt[1][0]=1; cf[1][0][0]=s3; ex[1][0][0][0]=1;
  cnt[1][1]=1; cf[1][1][0]=s3; ex[1][1][0][1]=1;
  cnt[1][2]=1; cf[1][2][0]=s3; ex[1][2][0][2]=1;
  cnt[2][0]=1; cf[2][0][0]=s15; ex[2][0][0][0]=1; ex[2][0][0][1]=1;
  cnt[2][1]=1; cf[2][1][0]=s15; ex[2][1][0][1]=1; ex[2][1][0][2]=1;
  cnt[2][2]=2; cf[2][2][0]=1.5*s5; ex[2][2][0][2]=2; cf[2][2][1]=-0.5*s5;
  cnt[2][3]=1; cf[2][3][0]=s15; ex[2][3][0][0]=1; ex[2][3][0][2]=1;
  cnt[2][4]=2; cf[2][4][0]=0.5*s15; ex[2][4][0][0]=2; cf[2][4][1]=-0.5*s15; ex[2][4][1][1]=2;
  if (t < 363){
    int p=0; while (t >= d_cgoffE[p+1]) p++;
    int l1=d_pl1[p], l2=d_pl2[p], l3=d_plo[p];
    int n2=2*l2+1, n3=2*l3+1;
    int loc = t - d_cgoffE[p];
    int k = loc % n3; int ij = loc / n3; int j = ij % n2; int i = ij / n2;
    double s=0.0;
    for (int t1=0;t1<cnt[l1][i];t1++)
      for (int t2=0;t2<cnt[l2][j];t2++)
        for (int t3=0;t3<cnt[l3][k];t3++){
          int a=ex[l1][i][t1][0]+ex[l2][j][t2][0]+ex[l3][k][t3][0];
          int b=ex[l1][i][t1][1]+ex[l2][j][t2][1]+ex[l3][k][t3][1];
          int c=ex[l1][i][t1][2]+ex[l2][j][t2][2]+ex[l3][k][t3][2];
          s += cf[l1][i][t1]*cf[l2][j][t2]*cf[l3][k][t3]*mavg_d(a,b,c);
        }
    Gs[t] = s;
  }
  __syncthreads();
  if (t < 11){
    double ssq=0.0;
    for (int q=d_cgoffE[t]; q<d_cgoffE[t+1]; q++) ssq += Gs[q]*Gs[q];
    scl[t] = sqrt((double)(2*d_plo[t]+1)/ssq);
  }
  __syncthreads();
  if (t < 363){
    int p=0; while (t >= d_cgoffE[p+1]) p++;
    cg[t] = (float)(Gs[t]*scl[p]);
  }
}

// ---------------- edge geometry ----------------
__global__ void __launch_bounds__(256) k0a(const float* __restrict__ posf, float* __restrict__ ef,
                   float* __restrict__ erbf, float* __restrict__ esh){
  int e = blockIdx.x*256 + threadIdx.x;
  if (e >= 6400) return;
  int b = e/1600; int r1 = e - b*1600; int i = r1/40; int j = r1 - i*40;
  float dx = posf[(b*40+j)*3+0] - posf[(b*40+i)*3+0];
  float dy = posf[(b*40+j)*3+1] - posf[(b*40+i)*3+1];
  float dz = posf[(b*40+j)*3+2] - posf[(b*40+i)*3+2];
  float sq = dx*dx+dy*dy+dz*dz;
  float em = (sq <= 36.f && sq > 1e-16f) ? 1.f : 0.f;
  ef[e] = em;
  float elen = (sq > 1e-12f) ? sqrtf(sq) : 0.f;
  float inv = 1.f/fmaxf(elen, 1e-8f);
  float x = dx*inv, y = dy*inv, z = dz*inv;
  float rc = fminf(elen, 6.f);
  #pragma unroll
  for (int k=0;k<16;k++){ float d = rc - 0.4f*(float)k; erbf[e*16+k] = expf(-6.25f*d*d); }
  const float S3=1.7320508075688772f, S5=2.23606797749979f, S15=3.872983346207417f;
  float* sh = esh + e*9;
  sh[0]=1.f; sh[1]=S3*x; sh[2]=S3*y; sh[3]=S3*z;
  sh[4]=S15*x*y; sh[5]=S15*y*z; sh[6]=0.5f*S5*(3.f*z*z-1.f); sh[7]=S15*x*z; sh[8]=0.5f*S15*(x*x-y*y);
}

// ---------------- node init + neighbor edge-list (deterministic ballot order, padded to even) ----------------
__global__ void __launch_bounds__(64) k0b(const int* __restrict__ z, const float* __restrict__ posf,
                  const float* __restrict__ zembf, const float* __restrict__ w_inf,
                  const float* __restrict__ ef,
                  float* __restrict__ x, float* __restrict__ deg,
                  int* __restrict__ nlist, int* __restrict__ ndeg2,
                  float* __restrict__ h2){
  int n = blockIdx.x; int lane = threadIdx.x;
  int b = n/40; int i = n - b*40;
  __shared__ float sc[81];
  float dx = posf[n*3+0]-posf[b*120+0];
  float dy = posf[n*3+1]-posf[b*120+1];
  float dz = posf[n*3+2]-posf[b*120+2];
  float sq = dx*dx+dy*dy+dz*dz;
  float r = (sq>1e-12f)? sqrtf(sq) : 0.f;
  sc[lane] = zembf[z[n]*64+lane];
  if (lane == 0) sc[64] = (i==0)?1.f:0.f;
  if (lane < 16){ float d = fminf(r,6.f)-0.4f*(float)lane; sc[65+lane] = expf(-6.25f*d*d); }
  // edge from src=lane to dst=i: e = b*1600 + lane*40 + i
  bool live = (lane < 40) && (ef[b*1600 + lane*40 + i] > 0.f);
  unsigned long long m = __ballot(live);
  if (live){
    int pos = __popcll(m & ((1ull<<lane)-1ull));
    nlist[n*64 + pos] = b*1600 + lane*40 + i;
  }
  if (lane == 0){
    int dg = __popcll(m);
    int dgp = (dg+1) & ~1;                 // pad to even with dummy edge 6400
    if (dg & 1) nlist[n*64 + dg] = 6400;
    ndeg2[n] = dgp;
    deg[n] = fmaxf((float)dg, 1.f);
  }
  if (n == 0){                             // zero dummy h2 row once per launch
    for (int c = lane; c < 129; c += 64) h2[6400*129 + c] = 0.f;
  }
  __syncthreads();
  float a = 0.f;
  for (int s=0;s<81;s++) a += sc[s]*w_inf[s*64+lane];
  x[n*240+lane] = a/9.f;
  for (int c = 64+lane; c < 240; c += 64) x[n*240+c] = 0.f;
}

// ---------------- fused edge MLP + Y (2 edges/block sharing src; also zeroes agg) ----------------
// edges 2B, 2B+1 always share src node (pairs never straddle a multiple of 40).
__global__ void __launch_bounds__(256) k12(const float* __restrict__ erbf, const float* __restrict__ wm1,
                   const float* __restrict__ bm1, const float* __restrict__ wm2,
                   const float* __restrict__ bm2, const float* __restrict__ ef,
                   const float* __restrict__ x, const float* __restrict__ esh,
                   const float* __restrict__ cg,
                   float* __restrict__ h2, float* __restrict__ Y, float* __restrict__ agg){
  int B = blockIdx.x;
  int t = threadIdx.x;
  if (B < 160){                            // zero agg for this layer (before any early exit)
    if (t < 240) agg[B*240 + t] = 0.f;
  }
  int e0 = B*2, e1 = B*2 + 1;
  float f0 = ef[e0], f1 = ef[e1];
  if (f0 == 0.f && f1 == 0.f) return;      // uniform: whole block exits
  int le = t >> 7, h = t & 127;            // half 0 -> e0 (waves 0,1), half 1 -> e1 (waves 2,3)
  int e = B*2 + le;
  bool liveh = (le ? f1 : f0) > 0.f;       // wave-uniform within each half
  __shared__ float h1L[2][128];
  __shared__ float xL[240];
  __shared__ float cgL[363];
  int src = e0/40;                         // shared src for both edges
  for (int c = t; c < 240; c += 256) xL[c] = x[src*240+c];
  for (int c = t; c < 363; c += 256) cgL[c] = cg[c];
  if (liveh){
    float a = bm1[h];
    #pragma unroll
    for (int k=0;k<16;k++) a += erbf[e*16+k]*wm1[k*128+h];
    h1L[le][h] = a/(1.f+expf(-a));
  }
  __syncthreads();
  if (!liveh) return;                      // wave-uniform exit for the dead half
  float a2 = bm2[h];
  #pragma unroll 8
  for (int k=0;k<128;k++) a2 += h1L[le][k]*wm2[k*128+h];
  float s = a2/(1.f+expf(-a2));
  h2[e*129+h] = s;
  if (h==0) h2[e*129+128] = 1.f;
  // ---- Y (permuted layout), 128 threads per edge ----
  float sh[9];
  #pragma unroll
  for (int q=0;q<9;q++) sh[q] = esh[e*9+q];
  int s2 = 0;
  for (int uk = h; uk < 1184; uk += 128){
    while (uk >= d_ybnd[s2+1]) s2++;
    int p = d_yperm[s2];
    int l1 = d_pl1[p], l2 = d_pl2[p], lo = d_plo[p];
    int dim1 = d_dims[l1], dim2 = d_dims[l2], dimo = d_dims[lo];
    int loc = uk - d_ybnd[s2];
    int u = loc/dimo; int k = loc - u*dimo;
    const float* C = cgL + d_cgoffE[p];
    int xb = d_segb[l1] + u*dim1;
    int shb = d_shb[l2];
    float acc = 0.f;
    for (int i2=0;i2<dim1;i2++){
      float Dik = 0.f;
      for (int j2=0;j2<dim2;j2++) Dik += sh[shb+j2]*C[(i2*dim2+j2)*dimo + k];
      acc += xL[xb+i2]*Dik;
    }
    Y[(size_t)e*1184+uk] = acc;
  }
}

// ---------------- w-contraction: bf16 via uint2, 4 w per thread, un=4 (round-15 exact) ----------------
template<int DD>
__device__ __forceinline__ void wcon(const ushort* __restrict__ wm3t, const ushort* __restrict__ bm3t,
    int h0, bool bias, const float* PLb, int wc, int Wp, int u0, int un,
    float* aggL, int outb){
  float acc[4*DD];
  #pragma unroll
  for (int q=0;q<4*DD;q++) acc[q]=0.f;
  for (int h=0; h<16; h++){
    const ushort* wrow = wm3t + (size_t)(h0+h)*13824 + wc;
    const float* pr = PLb + h*PLW;
    #pragma unroll 4
    for (int u=u0; u<u0+un; u++){
      uint2 wv = *(const uint2*)(wrow + u*Wp);
      const float* pp = pr + u*DD;
      #pragma unroll
      for (int k=0;k<DD;k++){
        float pv = pp[k];
        acc[0*DD+k] += __uint_as_float(wv.x << 16)*pv;
        acc[1*DD+k] += __uint_as_float(wv.x & 0xFFFF0000u)*pv;
        acc[2*DD+k] += __uint_as_float(wv.y << 16)*pv;
        acc[3*DD+k] += __uint_as_float(wv.y & 0xFFFF0000u)*pv;
      }
    }
  }
  if (bias){
    const ushort* wrow = bm3t + wc;
    const float* pr = PLb + 16*PLW;
    #pragma unroll 4
    for (int u=u0; u<u0+un; u++){
      uint2 wv = *(const uint2*)(wrow + u*Wp);
      const float* pp = pr + u*DD;
      #pragma unroll
      for (int k=0;k<DD;k++){
        float pv = pp[k];
        acc[0*DD+k] += __uint_as_float(wv.x << 16)*pv;
        acc[1*DD+k] += __uint_as_float(wv.x & 0xFFFF0000u)*pv;
        acc[2*DD+k] += __uint_as_float(wv.y << 16)*pv;
        acc[3*DD+k] += __uint_as_float(wv.y & 0xFFFF0000u)*pv;
      }
    }
  }
  #pragma unroll
  for (int j=0;j<4;j++)
    #pragma unroll
    for (int k=0;k<DD;k++)
      atomicAdd(&aggL[outb + j*DD + k], acc[j*DD+k]);
}

// ---------------- fused TP: P-build (edge-list, x2 unroll) + w-contraction (round-15 exact) ----------------
// grid (160, 8, 5): x = node n (fastest), y = h-chunk hc of 16 [+bias row hc==7], z = phase.
__global__ void __launch_bounds__(256) k34(const float* __restrict__ h2,
        const float* __restrict__ Y, const ushort* __restrict__ wm3t,
        const ushort* __restrict__ bm3t, const int* __restrict__ nlist,
        const int* __restrict__ ndeg2, float* __restrict__ agg){
  __shared__ float PL[17*PLW];
  __shared__ float aggL[240];
  int n = blockIdx.x, hc = blockIdx.y, ph = blockIdx.z;
  int t = threadIdx.x;
  int h0 = hc*16;
  bool bias = (hc==7);
  const int* nl = nlist + n*64;
  int dg2 = ndeg2[n];
  for (int q=t; q<240; q+=256) aggL[q]=0.f;

  int base = d_phb5[ph], width = d_phb5[ph+1] - base;
  // ---- P-build: PL[h, c] = sum_q h2[e_q, h0+h] * Y[e_q, base+c], 2 edges in flight ----
  for (int cc = t; cc < width; cc += 256){
    float pacc[17];
    #pragma unroll
    for (int h=0;h<17;h++) pacc[h]=0.f;
    for (int q=0; q<dg2; q+=2){
      int e0 = nl[q], e1 = nl[q+1];                       // wave-uniform s_loads
      float yv0 = Y[(size_t)e0*1184 + base + cc];
      float yv1 = Y[(size_t)e1*1184 + base + cc];
      const float* hh0 = h2 + e0*129 + h0;
      const float* hh1 = h2 + e1*129 + h0;
      #pragma unroll
      for (int h=0;h<17;h++) pacc[h] += yv0*hh0[h] + yv1*hh1[h];
    }
    #pragma unroll
    for (int h=0;h<17;h++) PL[h*PLW+cc] = pacc[h];
  }
  __syncthreads();
  // ---- w-contraction: every thread un=4 (64-load chain) ----
  if (ph==0){        // {p0}
    { int w4=t&15; int uc=t>>4;          wcon<1>(wm3t,bm3t,h0,bias, PL+0,   d_woff[0]+w4*4, 64, uc*4, 4, aggL, 0+w4*4); }
  } else if (ph==1){ // {p1 yloc 0, p3 yloc 32}
    if      (t<128){ int w4=t&15; int uc=t>>4;            wcon<1>(wm3t,bm3t,h0,bias, PL+0,  d_woff[1]+w4*4, 64, uc*4, 4, aggL, 0+w4*4); }
    else           { int tt=t-128; int w4=tt&7; int uc=tt>>3; wcon<3>(wm3t,bm3t,h0,bias, PL+32, d_woff[3]+w4*4, 32, uc*4, 4, aggL, 64+w4*12); }
  } else if (ph==2){ // {p2 yloc 0, p4 yloc 16, p5 yloc 112, p6 yloc 208}
    if      (t<64) { int w4=t&15; int uc=t>>4;            wcon<1>(wm3t,bm3t,h0,bias, PL+0,   d_woff[2]+w4*4, 64, uc*4, 4, aggL, 0+w4*4); }
    else if (t<128){ int tt=t-64;  int w4=tt&7; int uc=tt>>3; wcon<3>(wm3t,bm3t,h0,bias, PL+16,  d_woff[4]+w4*4, 32, uc*4, 4, aggL, 64+w4*12); }
    else if (t<192){ int tt=t-128; int w4=tt&7; int uc=tt>>3; wcon<3>(wm3t,bm3t,h0,bias, PL+112, d_woff[5]+w4*4, 32, uc*4, 4, aggL, 64+w4*12); }
    else if (t<224){ int tt=t-192; int w4=tt&7; int uc=tt>>3; wcon<3>(wm3t,bm3t,h0,bias, PL+208, d_woff[6]+w4*4, 32, uc*4, 4, aggL, 64+w4*12); }
  } else if (ph==3){ // {p7}
    if (t<64)      { int w4=t&3; int uc=t>>2;             wcon<5>(wm3t,bm3t,h0,bias, PL+0,   d_woff[7]+w4*4, 16, uc*4, 4, aggL, 160+w4*20); }
  } else {           // {p8 yloc 0, p9 yloc 160, p10 yloc 240}
    if      (t<32) { int w4=t&3; int uc=t>>2;             wcon<5>(wm3t,bm3t,h0,bias, PL+0,   d_woff[8]+w4*4, 16, uc*4, 4, aggL, 160+w4*20); }
    else if (t<48) { int tt=t-32; int w4=tt&3; int uc=tt>>2; wcon<5>(wm3t,bm3t,h0,bias, PL+160, d_woff[9]+w4*4, 16, uc*4, 4, aggL, 160+w4*20); }
    else if (t<64) { int tt=t-48; int w4=tt&3; int uc=tt>>2; wcon<5>(wm3t,bm3t,h0,bias, PL+240, d_woff[10]+w4*4,16, uc*4, 4, aggL, 160+w4*20); }
  }
  __syncthreads();
  int beg = d_obeg5[ph], end = d_oend5[ph];
  for (int q = beg + t; q < end; q += 256) atomicAdd(&agg[n*240 + q], aggL[q]);
}

// ---------------- node update: x += irlin(x,ws) + irlin(agg_scaled,wo) ----------------
__global__ void __launch_bounds__(256) k5_update(const float* __restrict__ x, const float* __restrict__ agg,
    const float* __restrict__ deg,
    const float* __restrict__ ws0,const float* __restrict__ ws1,const float* __restrict__ ws2,
    const float* __restrict__ wo0,const float* __restrict__ wo1,const float* __restrict__ wo2,
    float* __restrict__ xn){
  int n = blockIdx.x; int t = threadIdx.x;
  __shared__ float xr[240], ar[240];
  float dg = deg[n];
  if (t < 240){
    float fan = (t<64)?112.f:((t<160)?144.f:128.f);
    xr[t] = x[n*240+t];
    ar[t] = agg[n*240+t]/(sqrtf(fan)*dg);
  }
  __syncthreads();
  if (t < 240){
    int lo  = (t<64)?0:((t<160)?1:2);
    int base= (lo==0)?0:((lo==1)?64:160);
    int mul = (lo==0)?64:((lo==1)?32:16);
    int d   = (lo==0)?1:((lo==1)?3:5);
    int loc = t - base; int wi = loc/d; int dd = loc - wi*d;
    const float* Ws = (lo==0)?ws0:((lo==1)?ws1:ws2);
    const float* Wo = (lo==0)?wo0:((lo==1)?wo1:wo2);
    float s1=0.f, s2=0.f;
    for (int u=0; u<mul; u++){
      s1 += xr[base+u*d+dd]*Ws[u*mul+wi];
      s2 += ar[base+u*d+dd]*Wo[u*mul+wi];
    }
    xn[n*240+t] = xr[t] + (s1+s2)*rsqrtf((float)mul);
  }
}

// ---------------- last-layer node update + fused LayerNorm -> d_out ----------------
__global__ void __launch_bounds__(256) k5_ln(const float* __restrict__ x, const float* __restrict__ agg,
    const float* __restrict__ deg,
    const float* __restrict__ ws0,const float* __restrict__ ws1,const float* __restrict__ ws2,
    const float* __restrict__ wo0,const float* __restrict__ wo1,const float* __restrict__ wo2,
    const float* __restrict__ g, const float* __restrict__ b2,
    const int* __restrict__ flag, void* outv){
  int n = blockIdx.x; int t = threadIdx.x;
  __shared__ float xr[240], ar[240];
  __shared__ float red[256];
  float dg = deg[n];
  if (t < 240){
    float fan = (t<64)?112.f:((t<160)?144.f:128.f);
    xr[t] = x[n*240+t];
    ar[t] = agg[n*240+t]/(sqrtf(fan)*dg);
  }
  __syncthreads();
  float val = 0.f;
  if (t < 240){
    int lo  = (t<64)?0:((t<160)?1:2);
    int base= (lo==0)?0:((lo==1)?64:160);
    int mul = (lo==0)?64:((lo==1)?32:16);
    int d   = (lo==0)?1:((lo==1)?3:5);
    int loc = t - base; int wi = loc/d; int dd = loc - wi*d;
    const float* Ws = (lo==0)?ws0:((lo==1)?ws1:ws2);
    const float* Wo = (lo==0)?wo0:((lo==1)?wo1:wo2);
    float s1=0.f, s2=0.f;
    for (int u=0; u<mul; u++){
      s1 += xr[base+u*d+dd]*Ws[u*mul+wi];
      s2 += ar[base+u*d+dd]*Wo[u*mul+wi];
    }
    val = xr[t] + (s1+s2)*rsqrtf((float)mul);
  }
  red[t] = (t<240) ? val : 0.f;
  __syncthreads();
  #pragma unroll
  for (int s=128; s>=1; s>>=1){
    if (t < s) red[t] += red[t+s];
    __syncthreads();
  }
  float mu = red[0] / 240.f;
  __syncthreads();
  float dv = (t<240) ? (val-mu) : 0.f;
  red[t] = dv*dv;
  __syncthreads();
  #pragma unroll
  for (int s=128; s>=1; s>>=1){
    if (t < s) red[t] += red[t+s];
    __syncthreads();
  }
  float rstd = rsqrtf(red[0]/240.f + 1e-5f);
  if (t < 240){
    float r = (val-mu)*rstd*g[t] + b2[t];
    if (*flag) ((bf16*)outv)[n*240+t] = __float2bfloat16(r);
    else       ((float*)outv)[n*240+t] = r;
  }
}

// ---------------- launcher ----------------
extern "C" void kernel_launch(void* const* d_in, const int* in_sizes, int n_in,
                              void* d_out, int out_size, void* d_ws, size_t ws_size,
                              hipStream_t stream){
  (void)in_sizes; (void)n_in; (void)out_size; (void)ws_size;
  char* ws = (char*)d_ws;
  size_t cur = 0;
  auto carve = [&](size_t bytes)->char*{ char* pp = ws+cur; cur += (bytes+255)&~(size_t)255; return pp; };
  int*   flag = (int*)  carve(4);
  float* cg   = (float*)carve(363*4);
  float* wf   = (float*)carve(100992ull*4);     // all small params (wm3/bm3 excluded)
  ushort* wm3h= (ushort*)carve(5349888ull*2);   // wm3 (5308416) + bm3 (41472) in bf16
  float* xA   = (float*)carve(160*240*4);
  float* xB   = (float*)carve(160*240*4);
  float* agg  = (float*)carve(160*240*4);
  float* deg  = (float*)carve(160*4);
  int*   nlist= (int*)  carve(160*64*4);
  int*   ndeg2= (int*)  carve(160*4);
  float* ef   = (float*)carve(6400*4);
  float* erbf = (float*)carve(6400*16*4);
  float* esh  = (float*)carve(6400*9*4);
  float* h2   = (float*)carve((size_t)6401*129*4);   // +1 dummy zero row
  float* Yb   = (float*)carve((size_t)6401*1184*4);  // +1 dummy row (never needs zeroing)

  static const int cnts[15]   = {480,6464,5184,6144,384,49152,384,12288,3072,768,12288,3072,768,240,240};
  static const int srcIdx[15] = {1,3,4,5,6,7,8,11,12,13,14,15,16,17,18};
  CvtTab tab; int off = 0; float* fp[15];
  for (int s=0;s<15;s++){ tab.src[s] = d_in[srcIdx[s]]; tab.off[s] = off; tab.cnt[s] = cnts[s]; fp[s] = wf + off; off += cnts[s]; }
  tab.total = off;
  float *posf=fp[0], *zembf=fp[1], *w_inf=fp[2], *wm1f=fp[3], *bm1f=fp[4], *wm2f=fp[5], *bm2f=fp[6],
        *ws0f=fp[7], *ws1f=fp[8], *ws2f=fp[9], *wo0f=fp[10], *wo1f=fp[11], *wo2f=fp[12],
        *lngf=fp[13], *lnbf=fp[14];
  ushort* bm3h = wm3h + 5308416;

  k_flag<<<1,64,0,stream>>>((const unsigned int*)d_in[17], flag);
  k_convert<<<(tab.total+255)/256,256,0,stream>>>(tab, flag, wf);
  k_wcvt2<<<(5349888+255)/256,256,0,stream>>>(d_in[9], d_in[10], flag, wm3h);
  k_cg<<<1,384,0,stream>>>(cg);
  k0a<<<25,256,0,stream>>>(posf, ef, erbf, esh);
  k0b<<<160,64,0,stream>>>((const int*)d_in[0], posf, zembf, w_inf, ef, xA, deg, nlist, ndeg2, h2);

  float* xcur = xA; float* xnxt = xB;
  for (int t=0;t<3;t++){
    k12<<<3200,256,0,stream>>>(erbf, wm1f + t*2048, bm1f + t*128, wm2f + t*16384, bm2f + t*128,
                               ef, xcur, esh, cg, h2, Yb, agg);
    const ushort* wm3t = wm3h + (size_t)t*1769472;
    const ushort* bm3t = bm3h + (size_t)t*13824;
    k34<<<dim3(160,8,5),256,0,stream>>>(h2, Yb, wm3t, bm3t, nlist, ndeg2, agg);
    if (t < 2){
      k5_update<<<160,256,0,stream>>>(xcur, agg, deg, ws0f+t*4096, ws1f+t*1024, ws2f+t*256,
                                      wo0f+t*4096, wo1f+t*1024, wo2f+t*256, xnxt);
    } else {
      k5_ln<<<160,256,0,stream>>>(xcur, agg, deg, ws0f+t*4096, ws1f+t*1024, ws2f+t*256,
                                  wo0f+t*4096, wo1f+t*1024, wo2f+t*256, lngf, lnbf, flag, d_out);
    }
    float* tmp = xcur; xcur = xnxt; xnxt = tmp;
  }
}